// Round 1
// baseline (58.315 us; speedup 1.0000x reference)
//
#include <hip/hip_runtime.h>
#include <math.h>

// GaussianScalarCompander — single-dispatch fused formulation.
//
// Previous version used two dispatches: a 1-block table builder (serialized on
// one CU) + the per-element map. Both kernels' raw work is ~3 us, but the timed
// region pays per-dispatch overhead and the serialized build. This version
// fuses everything into ONE kernel: each block rebuilds the 1024-entry
// cdf/x_hat tables in LDS (4 entries/thread, ~360 VALU instrs — overlapped
// with the global x load issued at kernel entry), then does the per-element
// map. No workspace usage at all.
//
// likelihood is computed at gather time as s_cdf[k+1]-s_cdf[k] — bitwise
// identical to the previous materialized lik table (same fp32 values, same
// subtraction).
//
// Outputs concatenated flat: x_hat[B], likelihood[B], y_hat[B].

#define B_ELEMS 262144
#define NC      1024
#define THREADS 256
#define EPT     2                               // elements per thread (float2)
#define BLOCKS  (B_ELEMS / (THREADS * EPT))     // 512 -> 2 blocks/CU, 2 waves/SIMD

#define INV_SQRT6 0.40824829046386302f
#define SQRT6     2.4494897427831781f
#define SQRT3     1.7320508075688772f

__global__ __launch_bounds__(THREADS) void compand_fused_kernel(
        const float* __restrict__ x, float* __restrict__ out) {
    __shared__ float s_cdf[NC + 1];   // CDF_Y(k/N), k = 0..1024
    __shared__ float s_xh[NC];        // sqrt(6)*erfinv(2*(k+0.5)/N - 1)
    const int t = threadIdx.x;

    // Issue the global load FIRST so its ~500-900 cycle latency hides under
    // the table-build VALU work below.
    const int i = (blockIdx.x * THREADS + t) * EPT;
    const float2 xv = *(const float2*)(x + i);

    // Build tables: thread t computes entries k = 4t .. 4t+3 (contiguous so
    // the erfinvf tail slow-path diverges only in the first/last wave).
#pragma unroll
    for (int r = 0; r < 4; ++r) {
        const int k = t * 4 + r;
        float c;
        if (k == 0) {
            c = 0.0f;                             // CDF_Y(0) = 0 exactly
        } else {
            const float v = (float)k * (1.0f / (float)NC);
            c = fmaf(0.5f, erff(SQRT3 * erfinvf(fmaf(v, 2.0f, -1.0f))), 0.5f);
        }
        s_cdf[k] = c;

        const float yh = ((float)k + 0.5f) * (1.0f / (float)NC);
        s_xh[k] = SQRT6 * erfinvf(fmaf(yh, 2.0f, -1.0f));
    }
    if (t == 0) s_cdf[NC] = 1.0f;                 // CDF_Y(1) = 1 exactly
    __syncthreads();

    // Per-element map: one erff + LDS gathers.
    const float y0 = fmaf(0.5f, erff(xv.x * INV_SQRT6), 0.5f);
    const float y1 = fmaf(0.5f, erff(xv.y * INV_SQRT6), 0.5f);
    int k0 = (int)(y0 * (float)NC);               // y >= 0, trunc == floor
    int k1 = (int)(y1 * (float)NC);
    k0 = max(0, min(NC - 1, k0));
    k1 = max(0, min(NC - 1, k1));

    *(float2*)(out + i) = make_float2(s_xh[k0], s_xh[k1]);
    *(float2*)(out + B_ELEMS + i) =
        make_float2(s_cdf[k0 + 1] - s_cdf[k0], s_cdf[k1 + 1] - s_cdf[k1]);
    *(float2*)(out + 2 * B_ELEMS + i) =
        make_float2(((float)k0 + 0.5f) * (1.0f / (float)NC),
                    ((float)k1 + 0.5f) * (1.0f / (float)NC));
}

extern "C" void kernel_launch(void* const* d_in, const int* in_sizes, int n_in,
                              void* d_out, int out_size, void* d_ws, size_t ws_size,
                              hipStream_t stream) {
    const float* x = (const float*)d_in[0];
    // d_in[1] (centers) unused: centers[k] = (k+0.5)/1024 exactly, derived analytically.
    float* out = (float*)d_out;
    (void)d_ws; (void)ws_size;                    // no workspace needed

    compand_fused_kernel<<<dim3(BLOCKS), dim3(THREADS), 0, stream>>>(x, out);
}